// Round 7
// baseline (841.461 us; speedup 1.0000x reference)
//
#include <hip/hip_runtime.h>

typedef unsigned int u32;
typedef float v2f __attribute__((ext_vector_type(2)));

#define DIM 16384
#define NT  512

// Swizzle v4 on 13-bit slots: bits1..3 ^= (bit4, bit6^bit8, bit7). Linear bijection.
// Rank-verified per-phase: A-r/w & C-read b128 rank3; B r/w b64 rank4; scatter rank3 (2-way, free).
__host__ __device__ constexpr u32 fslot(u32 s) {
    return s ^ (((s >> 4) & 1u) << 1)
             ^ ((((s >> 6) ^ (s >> 8)) & 1u) << 2)
             ^ (((s >> 7) & 1u) << 3);
}

// CNOT-ring basis map (HW-validated R2-R6): M(y)_b = XOR_{p>=b} y_p (b<=12),
// M(y)_13 = XOR_{p<=12} y_p. GF(2)-linear.
__host__ __device__ constexpr u32 mmap(u32 y) {
    u32 s = y;
    s ^= s >> 1; s ^= s >> 2; s ^= s >> 4; s ^= s >> 8;
    return (s & 0x1FFFu) | (((s ^ (y >> 13)) & 1u) << 13);
}

// B<->C exchange compaction: drop bit 10 (split bit), keep 13 bits.
__host__ __device__ constexpr u32 bcmap(u32 y) {
    return (y & 0x3FFu) | (((y >> 11) & 7u) << 10);
}

__device__ __forceinline__ void rot2(v2f& a0, v2f& a1, v2f cv, v2f sv, v2f nsv) {
    v2f t0 = cv * a0;
    v2f t1 = cv * a1;
    v2f n0 = __builtin_elementwise_fma(nsv, a1, t0);
    v2f n1 = __builtin_elementwise_fma(sv,  a0, t1);
    a0 = n0; a1 = n1;
}

template<int D>
__device__ __forceinline__ void gate32(v2f (&am)[32], float c, float s) {
    v2f cv = {c, c}, sv = {s, s}, nsv = {-s, -s};
    #pragma unroll
    for (int r = 0; r < 32; ++r) if (!(r & D)) rot2(am[r], am[r | D], cv, sv, nsv);
}

// ---- Exchange A->B: split bit y13, slot = y & 0x1FFF. Unbalanced reader (B thread y13 fixed).
__device__ __forceinline__ void exAB(int tid, float* buf, v2f (&am)[32], v2f (&tmp)[16]) {
    float4* b4 = (float4*)buf;
    float2* b2 = (float2*)buf;
    u32 sA = fslot((u32)tid << 2);
    u32 sB = fslot(((u32)tid & 63u) | ((((u32)tid >> 6) & 3u) << 11));
    int myv = (tid >> 8) & 1;
    // sub-round 0: write y13=0 half (h 0..3)
    #pragma unroll
    for (int h = 0; h < 4; ++h)
        #pragma unroll
        for (int m = 0; m < 2; ++m) {
            u32 f4 = (sA ^ fslot(((u32)h << 11) | ((u32)m << 1))) >> 1;
            int r = h * 4 + m * 2;
            b4[f4] = make_float4(am[r].x, am[r].y, am[r + 1].x, am[r + 1].y);
        }
    __syncthreads();
    if (myv == 0) {
        #pragma unroll
        for (int j = 0; j < 16; ++j) {
            float2 t = b2[sB ^ fslot((u32)j << 6)]; am[j].x = t.x; am[j].y = t.y;
        }
        #pragma unroll
        for (int j = 16; j < 32; ++j) {
            float2 t = b2[sB ^ fslot((u32)j << 6)]; tmp[j - 16].x = t.x; tmp[j - 16].y = t.y;
        }
    }
    __syncthreads();
    // sub-round 1: write y13=1 half (h 4..7)
    #pragma unroll
    for (int h = 4; h < 8; ++h)
        #pragma unroll
        for (int m = 0; m < 2; ++m) {
            u32 f4 = (sA ^ fslot((((u32)h & 3u) << 11) | ((u32)m << 1))) >> 1;
            int r = h * 4 + m * 2;
            b4[f4] = make_float4(am[r].x, am[r].y, am[r + 1].x, am[r + 1].y);
        }
    __syncthreads();
    if (myv == 1) {
        #pragma unroll
        for (int j = 0; j < 32; ++j) {
            float2 t = b2[sB ^ fslot((u32)j << 6)]; am[j].x = t.x; am[j].y = t.y;
        }
    } else {
        #pragma unroll
        for (int j = 0; j < 16; ++j) am[16 + j] = tmp[j];
    }
    __syncthreads();
}

// ---- Exchange B->C: split bit y10, slot = bcmap(y). Unbalanced reader (C thread y10 fixed).
__device__ __forceinline__ void exBC(int tid, float* buf, v2f (&am)[32], v2f (&tmp)[16]) {
    float4* b4 = (float4*)buf;
    float2* b2 = (float2*)buf;
    u32 sW = fslot(bcmap(((u32)tid & 63u) | (((u32)tid >> 6) << 11)));
    u32 sR = fslot(bcmap((((u32)tid & 1u) << 1) | (((u32)tid >> 1) << 6)));
    int myv = (tid >> 5) & 1;
    // sub-round 0: write y10=0 half (j 0..15)
    #pragma unroll
    for (int j = 0; j < 16; ++j)
        b2[sW ^ fslot((u32)j << 6)] = make_float2(am[j].x, am[j].y);
    __syncthreads();
    if (myv == 0) {
        #pragma unroll
        for (int h = 0; h < 8; ++h) {
            float4 v = b4[(sR ^ fslot((u32)h << 2)) >> 1];
            am[h * 2].x = v.x; am[h * 2].y = v.y; am[h * 2 + 1].x = v.z; am[h * 2 + 1].y = v.w;
        }
        #pragma unroll
        for (int h = 8; h < 16; ++h) {
            float4 v = b4[(sR ^ fslot((u32)h << 2)) >> 1];
            int r = (h - 8) * 2;
            tmp[r].x = v.x; tmp[r].y = v.y; tmp[r + 1].x = v.z; tmp[r + 1].y = v.w;
        }
    }
    __syncthreads();
    // sub-round 1: write y10=1 half (j 16..31)
    #pragma unroll
    for (int j = 16; j < 32; ++j)
        b2[sW ^ fslot((u32)(j & 15) << 6)] = make_float2(am[j].x, am[j].y);
    __syncthreads();
    if (myv == 1) {
        #pragma unroll
        for (int h = 0; h < 16; ++h) {
            float4 v = b4[(sR ^ fslot((u32)h << 2)) >> 1];
            am[h * 2].x = v.x; am[h * 2].y = v.y; am[h * 2 + 1].x = v.z; am[h * 2 + 1].y = v.w;
        }
    } else {
        #pragma unroll
        for (int j = 0; j < 16; ++j) am[16 + j] = tmp[j];
    }
    __syncthreads();
}

// ---- Exchange C->A with M-scatter: split on TARGET bit t13 (balanced both sides).
// slot = M(y) & 0x1FFF. Writer picks per-h which pair element has t13==v (cndmask).
__device__ __forceinline__ void exCA(int tid, float* buf, v2f (&am)[32], v2f (&tmp)[16]) {
    float4* b4 = (float4*)buf;
    float2* b2 = (float2*)buf;
    u32 ybase = (((u32)tid & 1u) << 1) | (((u32)tid >> 1) << 6);
    u32 sW = fslot(mmap(ybase) & 0x1FFFu);
    u32 sA = fslot((u32)tid << 2);
    u32 P = (u32)__builtin_popcount(ybase & 0x1FFFu) & 1u;
    // sub-round 0: write the t13==0 element of each pair: q = P ^ pc(h)
    #pragma unroll
    for (int h = 0; h < 16; ++h) {
        u32 pc = (u32)(__builtin_popcount((unsigned)h) & 1);
        u32 q = P ^ pc;
        u32 slot = sW ^ fslot(mmap((u32)h << 2) & 0x1FFFu) ^ q;
        v2f val = q ? am[h * 2 + 1] : am[h * 2];
        b2[slot] = make_float2(val.x, val.y);
    }
    __syncthreads();
    #pragma unroll
    for (int h = 0; h < 4; ++h)
        #pragma unroll
        for (int m = 0; m < 2; ++m) {
            float4 v = b4[(sA ^ fslot(((u32)h << 11) | ((u32)m << 1))) >> 1];
            int r = h * 4 + m * 2;
            tmp[r].x = v.x; tmp[r].y = v.y; tmp[r + 1].x = v.z; tmp[r + 1].y = v.w;
        }
    __syncthreads();
    // sub-round 1: the t13==1 elements: q = P ^ pc(h) ^ 1
    #pragma unroll
    for (int h = 0; h < 16; ++h) {
        u32 pc = (u32)(__builtin_popcount((unsigned)h) & 1);
        u32 q = P ^ pc ^ 1u;
        u32 slot = sW ^ fslot(mmap((u32)h << 2) & 0x1FFFu) ^ q;
        v2f val = q ? am[h * 2 + 1] : am[h * 2];
        b2[slot] = make_float2(val.x, val.y);
    }
    __syncthreads();
    #pragma unroll
    for (int h = 4; h < 8; ++h)
        #pragma unroll
        for (int m = 0; m < 2; ++m) {
            float4 v = b4[(sA ^ fslot((((u32)h & 3u) << 11) | ((u32)m << 1))) >> 1];
            int r = h * 4 + m * 2;
            am[r].x = v.x; am[r].y = v.y; am[r + 1].x = v.z; am[r + 1].y = v.w;
        }
    #pragma unroll
    for (int r = 0; r < 16; ++r) am[r] = tmp[r];
    __syncthreads();
}

template<int L>
__device__ __forceinline__ void gatesA(const float* angC, const float* angS, v2f (&am)[32]) {
    gate32< 1>(am, angC[L * 16 +  0], angS[L * 16 +  0]);  // y0
    gate32< 2>(am, angC[L * 16 +  1], angS[L * 16 +  1]);  // y1
    gate32< 4>(am, angC[L * 16 + 11], angS[L * 16 + 11]);  // y11
    gate32< 8>(am, angC[L * 16 + 12], angS[L * 16 + 12]);  // y12
    gate32<16>(am, angC[L * 16 + 13], angS[L * 16 + 13]);  // y13
}
template<int L>
__device__ __forceinline__ void gatesB(const float* angC, const float* angS, v2f (&am)[32]) {
    gate32< 1>(am, angC[L * 16 +  6], angS[L * 16 +  6]);
    gate32< 2>(am, angC[L * 16 +  7], angS[L * 16 +  7]);
    gate32< 4>(am, angC[L * 16 +  8], angS[L * 16 +  8]);
    gate32< 8>(am, angC[L * 16 +  9], angS[L * 16 +  9]);
    gate32<16>(am, angC[L * 16 + 10], angS[L * 16 + 10]);
}
template<int L>
__device__ __forceinline__ void gatesC(const float* angC, const float* angS, v2f (&am)[32]) {
    gate32< 2>(am, angC[L * 16 + 2], angS[L * 16 + 2]);  // y2
    gate32< 4>(am, angC[L * 16 + 3], angS[L * 16 + 3]);
    gate32< 8>(am, angC[L * 16 + 4], angS[L * 16 + 4]);
    gate32<16>(am, angC[L * 16 + 5], angS[L * 16 + 5]);
}

__global__ __launch_bounds__(NT, 4) void qsim_kernel(
    const float* __restrict__ sreal, const float* __restrict__ simag,
    const float* __restrict__ wts,   const float* __restrict__ hw,
    const float* __restrict__ hb,    float* __restrict__ out)
{
    extern __shared__ float smem[];
    float* buf    = smem;                 // 16384 floats = 8192 float2 = 64 KB
    float* angC   = smem + 16384;
    float* angS   = angC + 48;
    float* lutLo  = angS + 48;
    float* lutHi  = lutLo + 128;
    float* redbuf = lutHi + 128;

    int tid = threadIdx.x;
    int b   = blockIdx.x;

    // global load, A-layout: float4 (h<<9)|tid covers y = (h<<11)|(tid<<2)|{0..3}
    const float4* pr = (const float4*)(sreal + (size_t)b * DIM);
    const float4* pi = (const float4*)(simag + (size_t)b * DIM);
    float4 vr[8], vi[8];
    #pragma unroll
    for (int h = 0; h < 8; ++h) {
        vr[h] = pr[(h << 9) | tid];
        vi[h] = pi[(h << 9) | tid];
    }

    // block-uniform setup: summed half-angles (3 RYs/wire/layer compose) + head LUTs
    if (tid < 42) {
        int l = tid / 14, bb = tid % 14, q = 13 - bb;   // bit bb <-> wire 13-bb
        float a = 0.5f * (wts[l * 42 + q] + wts[l * 42 + 14 + q] + wts[l * 42 + 28 + q]);
        angC[l * 16 + bb] = cosf(a);
        angS[l * 16 + bb] = sinf(a);
    } else if (tid >= 64 && tid < 192) {
        int i = tid - 64;           // low 7 index bits -> wires 13..7
        float ssum = 0.f;
        for (int bb = 0; bb < 7; ++bb) if ((i >> bb) & 1) ssum += hw[13 - bb];
        lutLo[i] = ssum;
    } else if (tid >= 192 && tid < 320) {
        int i = tid - 192;          // high 7 index bits -> wires 6..0
        float ssum = 0.f;
        for (int bb = 0; bb < 7; ++bb) if ((i >> bb) & 1) ssum += hw[6 - bb];
        lutHi[i] = ssum;
    }

    v2f am[32];
    v2f tmp[16];
    #pragma unroll
    for (int h = 0; h < 8; ++h) {
        am[h * 4 + 0].x = vr[h].x; am[h * 4 + 0].y = vi[h].x;
        am[h * 4 + 1].x = vr[h].y; am[h * 4 + 1].y = vi[h].y;
        am[h * 4 + 2].x = vr[h].z; am[h * 4 + 2].y = vi[h].z;
        am[h * 4 + 3].x = vr[h].w; am[h * 4 + 3].y = vi[h].w;
    }

    __syncthreads();
    float W0  = lutLo[127] + lutHi[127];   // sum of all head weights
    float acc = 0.f;

    // Layer 0
    gatesA<0>(angC, angS, am); exAB(tid, buf, am, tmp);
    gatesB<0>(angC, angS, am); exBC(tid, buf, am, tmp);
    gatesC<0>(angC, angS, am); exCA(tid, buf, am, tmp);
    // Layer 1
    gatesA<1>(angC, angS, am); exAB(tid, buf, am, tmp);
    gatesB<1>(angC, angS, am); exBC(tid, buf, am, tmp);
    gatesC<1>(angC, angS, am); exCA(tid, buf, am, tmp);
    // Layer 2
    gatesA<2>(angC, angS, am); exAB(tid, buf, am, tmp);
    gatesB<2>(angC, angS, am); exBC(tid, buf, am, tmp);
    gatesC<2>(angC, angS, am);

    // fused measurement: permute labels by M, weighted |amp|^2 reduce
    {
        u32 ybase = (((u32)tid & 1u) << 1) | (((u32)tid >> 1) << 6);
        u32 myb = mmap(ybase);
        #pragma unroll
        for (int h = 0; h < 16; ++h) {
            #pragma unroll
            for (int q = 0; q < 2; ++q) {
                u32 yp = myb ^ mmap(((u32)h << 2) | (u32)q);
                int r = h * 2 + q;
                float p  = fmaf(am[r].x, am[r].x, am[r].y * am[r].y);
                float wv = W0 - 2.0f * (lutLo[yp & 127u] + lutHi[yp >> 7]);
                acc = fmaf(wv, p, acc);
            }
        }
    }

    // block reduction
    #pragma unroll
    for (int off = 32; off > 0; off >>= 1) acc += __shfl_xor(acc, off, 64);
    if ((tid & 63) == 0) redbuf[tid >> 6] = acc;
    __syncthreads();
    if (tid == 0) {
        float tot = hb[0];
        #pragma unroll
        for (int i = 0; i < 8; ++i) tot += redbuf[i];
        out[b] = tot;
    }
}

extern "C" void kernel_launch(void* const* d_in, const int* in_sizes, int n_in,
                              void* d_out, int out_size, void* d_ws, size_t ws_size,
                              hipStream_t stream)
{
    const float* sreal = (const float*)d_in[0];
    const float* simag = (const float*)d_in[1];
    const float* wts   = (const float*)d_in[2];
    const float* hw    = (const float*)d_in[3];
    const float* hb    = (const float*)d_in[4];
    float* out = (float*)d_out;

    int batch = in_sizes[0] / DIM;
    size_t smem_bytes = (16384 + 48 + 48 + 128 + 128 + 16) * sizeof(float);  // 67008 B -> 2 blocks/CU

    (void)hipFuncSetAttribute((const void*)qsim_kernel,
                              hipFuncAttributeMaxDynamicSharedMemorySize, (int)smem_bytes);
    qsim_kernel<<<dim3(batch), dim3(NT), smem_bytes, stream>>>(sreal, simag, wts, hw, hb, out);
}